// Round 2
// baseline (113.830 us; speedup 1.0000x reference)
//
#include <hip/hip_runtime.h>
#include <math.h>

// Hawkes loglik/compensator, B=4 N=2048 K=50 D=4.
// R2 structure: 2 kernels.
//  pair_kernel: 144 blocks = 4 batches x 36 lower-tri (ti,tj) 256x256 tile
//    pairs, 1024 threads (4 j-splits x 256 i). Full softplus(alpha) table in
//    LDS as 4 planes [ty][c] stride 51 (conflict-free random-ty gather).
//    Writes per-(b, j-tile, i) partial sums to ws.
//  finalize_kernel: 4 blocks; computes mhat/colsum inline, sums partials,
//    log+mask reduce, compensator, writes 8 outputs.

#define NT 50
#define ND 4
#define NB 4
#define NN 2048
#define TILE 256
#define NTI (NN / TILE)              // 8 tiles per batch
#define NPAIR (NTI * (NTI + 1) / 2)  // 36
#define APLANE (NT * 51)             // 2550 floats per decay plane
#define THREADS 1024

__device__ __forceinline__ float softplus_stable(float x) {
    // matches jax.nn.softplus: max(x,0) + log1p(exp(-|x|))
    return fmaxf(x, 0.0f) + log1pf(__expf(-fabsf(x)));
}

// ---------------- pair kernel ----------------
__global__ __launch_bounds__(THREADS) void pair_kernel(
        const float* __restrict__ times,
        const int*   __restrict__ types,
        const float* __restrict__ alpha_p,
        const float* __restrict__ beta_p,
        float* __restrict__ pr) {
    __shared__ float A_lds[ND * APLANE];   // 40800 B: plane d at d*APLANE, [ty*51 + c]
    __shared__ float sh_tj[TILE];
    __shared__ int   sh_tc[TILE];
    __shared__ float sh_part[3][TILE];

    int blk = blockIdx.x;
    int b = blk / NPAIR;
    int p = blk - b * NPAIR;
    int ti = 0;
    while (p >= ti + 1) { p -= ti + 1; ti++; }
    int tj = p;   // tj <= ti

    int tid = threadIdx.x;

    float w0 = softplus_stable(beta_p[0]);
    float w1 = softplus_stable(beta_p[1]);
    float w2 = softplus_stable(beta_p[2]);
    float w3 = softplus_stable(beta_p[3]);

    // stage softplus(alpha) -> 4 LDS planes; alpha layout [k][c][d] flat
    for (int idx = tid; idx < NT * NT * ND; idx += THREADS) {
        int k   = idx / (NT * ND);          // 0..49 (target type)
        int rem = idx - k * (NT * ND);
        int c   = rem >> 2;                 // 0..49 (source type)
        int d   = rem & 3;
        A_lds[d * APLANE + k * 51 + c] = softplus_stable(alpha_p[idx]);
    }
    // stage j-tile times/types
    if (tid < TILE) {
        sh_tj[tid] = times[b * NN + tj * TILE + tid];
        sh_tc[tid] = types[b * NN + tj * TILE + tid];
    }

    int i_loc  = tid & (TILE - 1);
    int split  = tid >> 8;                  // 0..3
    int ig     = ti * TILE + i_loc;
    float t_i  = times[b * NN + ig];
    int   ty   = types[b * NN + ig];
    __syncthreads();

    const float* Arow = &A_lds[ty * 51];    // + c, +APLANE+c, ... per decay
    int jmax = (ti == tj) ? i_loc : TILE;   // strict lower triangle

    float a0 = 0.f, a1 = 0.f, a2 = 0.f, a3 = 0.f;
    for (int jl = split; jl < jmax; jl += 4) {
        float dt = t_i - sh_tj[jl];
        int   c  = sh_tc[jl];
        float e0 = __expf(-w0 * dt);
        float e1 = __expf(-w1 * dt);
        float e2 = __expf(-w2 * dt);
        float e3 = __expf(-w3 * dt);
        a0 = fmaf(Arow[c],              e0, a0);
        a1 = fmaf(Arow[APLANE + c],     e1, a1);
        a2 = fmaf(Arow[2 * APLANE + c], e2, a2);
        a3 = fmaf(Arow[3 * APLANE + c], e3, a3);
    }
    float partial = w0 * a0 + w1 * a1 + w2 * a2 + w3 * a3;

    if (split) sh_part[split - 1][i_loc] = partial;
    __syncthreads();
    if (split == 0) {
        float tot = partial + sh_part[0][i_loc] + sh_part[1][i_loc] + sh_part[2][i_loc];
        pr[(b * NTI + tj) * NN + ig] = tot;   // unique writer per slot
    }
}

// ---------------- finalize kernel (NB blocks x 256) ----------------
__global__ __launch_bounds__(256) void finalize_kernel(
        const float* __restrict__ times,
        const int*   __restrict__ types,
        const float* __restrict__ mask,
        const float* __restrict__ t0,
        const float* __restrict__ t1,
        const float* __restrict__ mu_p,
        const float* __restrict__ alpha_p,
        const float* __restrict__ beta_p,
        const float* __restrict__ pr,
        float* __restrict__ out) {
    __shared__ float colsum[NT * ND];   // [c*4 + d] = sum_k softplus(alpha[k][c][d])
    __shared__ float mh[NT];
    __shared__ float red[8];

    int b = blockIdx.x;
    int tid = threadIdx.x;

    float w0 = softplus_stable(beta_p[0]);
    float w1 = softplus_stable(beta_p[1]);
    float w2 = softplus_stable(beta_p[2]);
    float w3 = softplus_stable(beta_p[3]);

    if (tid < NT * ND) {
        float s = 0.f;
        #pragma unroll 5
        for (int k = 0; k < NT; ++k)
            s += softplus_stable(alpha_p[k * (NT * ND) + tid]);
        colsum[tid] = s;
    } else if (tid >= 200 && tid < 200 + NT) {
        mh[tid - 200] = softplus_stable(mu_p[tid - 200]);
    }
    __syncthreads();

    float T1 = t1[b];
    float ll = 0.f, cp = 0.f;
    for (int k = 0; k < NN / 256; ++k) {
        int i   = k * 256 + tid;
        int gi  = b * NN + i;
        int ty  = types[gi];
        float m = mask[gi];
        // sum partials over contributing j-tiles
        float s = 0.f;
        int tmax = i >> 8;
        for (int tj = 0; tj <= tmax; ++tj)
            s += pr[(b * NTI + tj) * NN + i];
        float rate = mh[ty] + s;
        ll += __logf(rate + 1e-8f) * m;
        // compensator term for event i
        float tt = T1 - times[gi];
        const float* cs = &colsum[ty * ND];
        cp += m * (cs[0] * (1.f - __expf(-w0 * tt)) +
                   cs[1] * (1.f - __expf(-w1 * tt)) +
                   cs[2] * (1.f - __expf(-w2 * tt)) +
                   cs[3] * (1.f - __expf(-w3 * tt)));
    }
    #pragma unroll
    for (int off = 32; off > 0; off >>= 1) {
        ll += __shfl_down(ll, off, 64);
        cp += __shfl_down(cp, off, 64);
    }
    if ((tid & 63) == 0) { red[tid >> 6] = ll; red[4 + (tid >> 6)] = cp; }
    __syncthreads();
    if (tid == 0) {
        float llt = red[0] + red[1] + red[2] + red[3];
        float cpt = red[4] + red[5] + red[6] + red[7];
        float sm = 0.f;
        #pragma unroll 10
        for (int k = 0; k < NT; ++k) sm += mh[k];
        out[b]      = llt;
        out[NB + b] = (T1 - t0[b]) * sm + cpt;
    }
}

extern "C" void kernel_launch(void* const* d_in, const int* in_sizes, int n_in,
                              void* d_out, int out_size, void* d_ws, size_t ws_size,
                              hipStream_t stream) {
    const float* times   = (const float*)d_in[0];
    const int*   types   = (const int*)  d_in[1];
    const float* mask    = (const float*)d_in[2];
    const float* t0      = (const float*)d_in[3];
    const float* t1      = (const float*)d_in[4];
    const float* mu_p    = (const float*)d_in[5];
    const float* alpha_p = (const float*)d_in[6];
    const float* beta_p  = (const float*)d_in[7];
    float* out = (float*)d_out;
    float* pr  = (float*)d_ws;   // NB*NTI*NN floats = 256 KB

    pair_kernel<<<NB * NPAIR, THREADS, 0, stream>>>(times, types, alpha_p, beta_p, pr);
    finalize_kernel<<<NB, 256, 0, stream>>>(times, types, mask, t0, t1,
                                            mu_p, alpha_p, beta_p, pr, out);
}